// Round 1
// baseline (117.510 us; speedup 1.0000x reference)
//
#include <hip/hip_runtime.h>

// CLAHE: B=32, C=3, H=W=512, GRID=8x8 -> TILE=64x64 (4096 px), NUM_BINS=256,
// CLIP_LIMIT=40 -> clip value = 640. LUT layout matches reference seg order:
// lut_idx = ((b*8+ty)*8+tx)*3 + c, 256 floats each -> 6144*256*4 = 6.29 MB in d_ws.

#define NBINS  256
#define TILE   64
#define CH     3
#define HH     512
#define WW     512
#define CLIPV  640
#define PIXELS 4096   // per tile

// ---------------- Kernel 1: histogram + clip + redistribute + cumsum -> LUT ----
__global__ __launch_bounds__(256) void clahe_hist_lut(const float* __restrict__ img,
                                                      float* __restrict__ luts) {
    const int bid = blockIdx.x;      // = ((b*8+ty)*8+tx)*3 + c
    const int t   = threadIdx.x;
    int c  = bid % 3;
    int r  = bid / 3;
    int tx = r % 8;  r /= 8;
    int ty = r % 8;
    int b  = r / 8;

    __shared__ unsigned int hist[NBINS];
    __shared__ int          scan[NBINS];
    hist[t] = 0u;
    __syncthreads();

    // 64x64 tile = 1024 float4; 256 threads x 4 iterations, coalesced.
    const float* base = img + ((size_t)(b * CH + c) * HH + (size_t)ty * TILE) * WW + (size_t)tx * TILE;
    #pragma unroll
    for (int j = 0; j < 4; ++j) {
        int f  = t + 256 * j;        // float4 index: 64 rows x 16 float4/row
        int y  = f >> 4;
        int x4 = f & 15;
        const float4 v = *reinterpret_cast<const float4*>(base + (size_t)y * WW + x4 * 4);
        int b0 = min(max((int)floorf(v.x * 256.0f), 0), 255);
        int b1 = min(max((int)floorf(v.y * 256.0f), 0), 255);
        int b2 = min(max((int)floorf(v.z * 256.0f), 0), 255);
        int b3 = min(max((int)floorf(v.w * 256.0f), 0), 255);
        atomicAdd(&hist[b0], 1u);
        atomicAdd(&hist[b1], 1u);
        atomicAdd(&hist[b2], 1u);
        atomicAdd(&hist[b3], 1u);
    }
    __syncthreads();

    // Clip, then inclusive scan (Hillis-Steele over LDS, 8 steps).
    int ci = min((int)hist[t], CLIPV);
    scan[t] = ci;
    __syncthreads();
    for (int off = 1; off < 256; off <<= 1) {
        int add = (t >= off) ? scan[t - off] : 0;
        __syncthreads();
        scan[t] += add;
        __syncthreads();
    }
    int total    = scan[255];
    int excess   = PIXELS - total;           // >= 0
    int residual = excess & 255;
    int redist   = excess >> 8;
    // inclusive cumsum of (clipped + redist + (bin<residual ? 1 : 0))
    int cum = scan[t] + redist * (t + 1) + min(t + 1, residual);
    // (nb-1)/pixels = 255/4096 is exact in fp32; cum*scale <= 255 exactly.
    float lut = floorf(fminf((float)cum * (255.0f / 4096.0f), 255.0f));
    luts[(size_t)bid * NBINS + t] = lut;
}

// ---------------- Kernel 2: bilinear LUT application ---------------------------
__device__ __forceinline__ void axis_map(int pos, int& t0, int& t1, float& w) {
    // T=64, G=8: inside = [32, 480)
    if (pos < 32)        { t0 = 0; t1 = 0; w = 1.0f; }
    else if (pos >= 480) { t0 = 7; t1 = 7; w = 1.0f; }
    else {
        int k  = (pos - 32) >> 6;   // 0..6
        int rr = (pos - 32) & 63;
        t0 = k; t1 = k + 1;
        w  = (float)(63 - rr) / 63.0f;
    }
}

__global__ __launch_bounds__(256) void clahe_apply(const float* __restrict__ img,
                                                   const float* __restrict__ luts,
                                                   float* __restrict__ out) {
    size_t g = (size_t)blockIdx.x * 256 + threadIdx.x;  // float4 index
    size_t p = g * 4;                                   // pixel index
    int plane = (int)(p >> 18);                         // b*3 + c   (512*512 = 2^18)
    int off   = (int)(p & 262143);
    int y = off >> 9;
    int x = off & 511;
    int c  = plane % 3;
    int bb = plane / 3;

    int ty0, ty1; float wy;
    axis_map(y, ty0, ty1, wy);
    const int rowbase0 = (bb * 8 + ty0) * 8;
    const int rowbase1 = (bb * 8 + ty1) * 8;

    float4 v = *reinterpret_cast<const float4*>(img + p);
    float pix[4] = {v.x, v.y, v.z, v.w};
    float res[4];
    #pragma unroll
    for (int i = 0; i < 4; ++i) {
        int xx = x + i;
        int tx0, tx1; float wx;
        axis_map(xx, tx0, tx1, wx);
        int vv = min(max((int)floorf(pix[i] * 255.0f), 0), 255);
        float L00 = luts[((size_t)((rowbase0 + tx0) * 3 + c)) * NBINS + vv];
        float L01 = luts[((size_t)((rowbase0 + tx1) * 3 + c)) * NBINS + vv];
        float L10 = luts[((size_t)((rowbase1 + tx0) * 3 + c)) * NBINS + vv];
        float L11 = luts[((size_t)((rowbase1 + tx1) * 3 + c)) * NBINS + vv];
        float o = wy * wx * L00 + wy * (1.0f - wx) * L01
                + (1.0f - wy) * wx * L10 + (1.0f - wy) * (1.0f - wx) * L11;
        res[i] = o / 255.0f;
    }
    float4 ov = make_float4(res[0], res[1], res[2], res[3]);
    *reinterpret_cast<float4*>(out + p) = ov;
}

extern "C" void kernel_launch(void* const* d_in, const int* in_sizes, int n_in,
                              void* d_out, int out_size, void* d_ws, size_t ws_size,
                              hipStream_t stream) {
    const float* img  = (const float*)d_in[0];
    float*       out  = (float*)d_out;
    float*       luts = (float*)d_ws;   // 6144 * 256 floats = 6.29 MB

    // Kernel 1: one block per (b,ty,tx,c)
    clahe_hist_lut<<<32 * 8 * 8 * 3, 256, 0, stream>>>(img, luts);
    // Kernel 2: 25,165,824 px / 4 per thread / 256 per block = 24576 blocks
    clahe_apply<<<24576, 256, 0, stream>>>(img, luts, out);
}

// Round 2
// 62.327 us; speedup vs baseline: 1.8854x; 1.8854x over previous
//
#include <hip/hip_runtime.h>

// CLAHE: B=32, C=3, H=W=512, GRID=8x8 -> TILE=64x64 (4096 px), NUM_BINS=256,
// CLIP_LIMIT=40 -> clip value = 640. LUT layout matches reference seg order:
// lut_idx = ((b*8+ty)*8+tx)*3 + c, 256 floats each -> 6144*256*4 = 6.29 MB in d_ws.

#define NBINS  256
#define TILE   64
#define CH     3
#define HH     512
#define WW     512
#define CLIPV  640
#define PIXELS 4096   // per tile

// ---------------- Kernel 1: histogram + clip + redistribute + cumsum -> LUT ----
__global__ __launch_bounds__(256) void clahe_hist_lut(const float* __restrict__ img,
                                                      float* __restrict__ luts) {
    const int bid = blockIdx.x;      // = ((b*8+ty)*8+tx)*3 + c
    const int t   = threadIdx.x;
    int c  = bid % 3;
    int r  = bid / 3;
    int tx = r % 8;  r /= 8;
    int ty = r % 8;
    int b  = r / 8;

    __shared__ unsigned int hist[NBINS];
    __shared__ int          scan[NBINS];
    hist[t] = 0u;
    __syncthreads();

    // 64x64 tile = 1024 float4; 256 threads x 4 iterations, coalesced.
    const float* base = img + ((size_t)(b * CH + c) * HH + (size_t)ty * TILE) * WW + (size_t)tx * TILE;
    #pragma unroll
    for (int j = 0; j < 4; ++j) {
        int f  = t + 256 * j;        // float4 index: 64 rows x 16 float4/row
        int y  = f >> 4;
        int x4 = f & 15;
        const float4 v = *reinterpret_cast<const float4*>(base + (size_t)y * WW + x4 * 4);
        int b0 = min(max((int)floorf(v.x * 256.0f), 0), 255);
        int b1 = min(max((int)floorf(v.y * 256.0f), 0), 255);
        int b2 = min(max((int)floorf(v.z * 256.0f), 0), 255);
        int b3 = min(max((int)floorf(v.w * 256.0f), 0), 255);
        atomicAdd(&hist[b0], 1u);
        atomicAdd(&hist[b1], 1u);
        atomicAdd(&hist[b2], 1u);
        atomicAdd(&hist[b3], 1u);
    }
    __syncthreads();

    // Clip, then inclusive scan (Hillis-Steele over LDS, 8 steps).
    int ci = min((int)hist[t], CLIPV);
    scan[t] = ci;
    __syncthreads();
    for (int off = 1; off < 256; off <<= 1) {
        int add = (t >= off) ? scan[t - off] : 0;
        __syncthreads();
        scan[t] += add;
        __syncthreads();
    }
    int total    = scan[255];
    int excess   = PIXELS - total;           // >= 0
    int residual = excess & 255;
    int redist   = excess >> 8;
    // inclusive cumsum of (clipped + redist + (bin<residual ? 1 : 0))
    int cum = scan[t] + redist * (t + 1) + min(t + 1, residual);
    // (nb-1)/pixels = 255/4096 is exact in fp32; cum*scale <= 255 exactly.
    float lut = floorf(fminf((float)cum * (255.0f / 4096.0f), 255.0f));
    luts[(size_t)bid * NBINS + t] = lut;
}

// ---------------- Kernel 2: bilinear LUT application ---------------------------
__device__ __forceinline__ void axis_map(int pos, int& t0, int& t1, float& w) {
    // T=64, G=8: inside = [32, 480)
    if (pos < 32)        { t0 = 0; t1 = 0; w = 1.0f; }
    else if (pos >= 480) { t0 = 7; t1 = 7; w = 1.0f; }
    else {
        int k  = (pos - 32) >> 6;   // 0..6
        int rr = (pos - 32) & 63;
        t0 = k; t1 = k + 1;
        w  = (float)(63 - rr) / 63.0f;
    }
}

// One block = 2 consecutive image rows of one (b,c) plane (1024 px).
// Stage y-combined LUTs in LDS: comb[row][tx][v] = wy*L(ty0) + (1-wy)*L(ty1).
// Rows 2r and 2r+1 always share (ty0,ty1) for T=64 (boundary rows are even).
__global__ __launch_bounds__(256) void clahe_apply(const float* __restrict__ img,
                                                   const float* __restrict__ luts,
                                                   float* __restrict__ out) {
    __shared__ float comb[2][8][NBINS];   // 16 KB

    const int t     = threadIdx.x;
    const int bid   = blockIdx.x;
    const int rp    = bid & 255;          // row pair 0..255
    const int plane = bid >> 8;           // b*3 + c, 0..95
    const int c     = plane % 3;
    const int bb    = plane / 3;
    const int y0    = rp * 2;
    const int y1    = y0 + 1;

    int ty0, ty1; float wy0, wy1, wdum;
    axis_map(y0, ty0, ty1, wy0);
    { int d0, d1; axis_map(y1, d0, d1, wy1); (void)d0; (void)d1; (void)wdum; }

    const int rowbase0 = (bb * 8 + ty0) * 8;   // tile-row base (LUT idx / (3*256) units)
    const int rowbase1 = (bb * 8 + ty1) * 8;

    // ---- stage: 16 coalesced LUT loads per thread (v = t), build combined rows
    #pragma unroll
    for (int tx = 0; tx < 8; ++tx) {
        float L0 = luts[((size_t)((rowbase0 + tx) * 3 + c)) * NBINS + t];
        float L1 = luts[((size_t)((rowbase1 + tx) * 3 + c)) * NBINS + t];
        comb[0][tx][t] = wy0 * L0 + (1.0f - wy0) * L1;
        comb[1][tx][t] = wy1 * L0 + (1.0f - wy1) * L1;
    }
    __syncthreads();

    // ---- apply: thread t handles float4 #t of the 2-row strip
    const int row = t >> 7;               // 0 or 1 (128 float4 per 512-px row)
    const int x   = (t & 127) * 4;
    const size_t p = ((size_t)plane << 18) + (size_t)(y0 + row) * WW + x;

    float4 v = *reinterpret_cast<const float4*>(img + p);
    float pix[4] = {v.x, v.y, v.z, v.w};
    float res[4];
    #pragma unroll
    for (int i = 0; i < 4; ++i) {
        int xx = x + i;
        int tx0, tx1; float wx;
        axis_map(xx, tx0, tx1, wx);
        int vv = min(max((int)floorf(pix[i] * 255.0f), 0), 255);
        float Lr0 = comb[row][tx0][vv];
        float Lr1 = comb[row][tx1][vv];
        res[i] = (wx * Lr0 + (1.0f - wx) * Lr1) * (1.0f / 255.0f);
    }
    float4 ov = make_float4(res[0], res[1], res[2], res[3]);
    *reinterpret_cast<float4*>(out + p) = ov;
}

extern "C" void kernel_launch(void* const* d_in, const int* in_sizes, int n_in,
                              void* d_out, int out_size, void* d_ws, size_t ws_size,
                              hipStream_t stream) {
    const float* img  = (const float*)d_in[0];
    float*       out  = (float*)d_out;
    float*       luts = (float*)d_ws;   // 6144 * 256 floats = 6.29 MB

    // Kernel 1: one block per (b,ty,tx,c)
    clahe_hist_lut<<<32 * 8 * 8 * 3, 256, 0, stream>>>(img, luts);
    // Kernel 2: one block per (plane, row-pair): 96 * 256 = 24576 blocks
    clahe_apply<<<24576, 256, 0, stream>>>(img, luts, out);
}

// Round 3
// 62.118 us; speedup vs baseline: 1.8917x; 1.0034x over previous
//
#include <hip/hip_runtime.h>

// CLAHE: B=32, C=3, H=W=512, GRID=8x8 -> TILE=64x64 (4096 px), NUM_BINS=256,
// CLIP_LIMIT=40 -> clip value = 640.
// d_ws layout: [0, 6.29MB) f32 LUTs (lut_idx = ((b*8+ty)*8+tx)*3 + c),
//              [6.29MB, +25.2MB) u8 quantized image v = clip(floor(img*255)).

#define NBINS  256
#define TILE   64
#define CH     3
#define HH     512
#define WW     512
#define CLIPV  640
#define PIXELS 4096   // per tile

#define LUTS_FLOATS (32 * 8 * 8 * 3 * NBINS)          // 1,572,864
#define V8_BYTES    ((size_t)32 * 3 * HH * WW)        // 25,165,824

// ---------------- Kernel 1: histogram + clip + redistribute + cumsum -> LUT ----
// Also emits the u8 quantized image for the apply pass (write_v8 != 0).
__global__ __launch_bounds__(256) void clahe_hist_lut(const float* __restrict__ img,
                                                      float* __restrict__ luts,
                                                      unsigned char* __restrict__ v8,
                                                      int write_v8) {
    const int bid = blockIdx.x;      // = ((b*8+ty)*8+tx)*3 + c
    const int t   = threadIdx.x;
    int c  = bid % 3;
    int r  = bid / 3;
    int tx = r % 8;  r /= 8;
    int ty = r % 8;
    int b  = r / 8;

    __shared__ unsigned int hist[NBINS];
    __shared__ int          scan[NBINS];
    hist[t] = 0u;
    __syncthreads();

    const int plane = b * CH + c;
    const float* base = img + ((size_t)plane * HH + (size_t)ty * TILE) * WW + (size_t)tx * TILE;
    unsigned char* v8base = v8 + ((size_t)plane * HH + (size_t)ty * TILE) * WW + (size_t)tx * TILE;

    // 64x64 tile = 1024 float4; 256 threads x 4 iterations, coalesced.
    #pragma unroll
    for (int j = 0; j < 4; ++j) {
        int f  = t + 256 * j;        // float4 index: 64 rows x 16 float4/row
        int y  = f >> 4;
        int x4 = f & 15;
        const float4 v = *reinterpret_cast<const float4*>(base + (size_t)y * WW + x4 * 4);
        int b0 = min(max((int)floorf(v.x * 256.0f), 0), 255);
        int b1 = min(max((int)floorf(v.y * 256.0f), 0), 255);
        int b2 = min(max((int)floorf(v.z * 256.0f), 0), 255);
        int b3 = min(max((int)floorf(v.w * 256.0f), 0), 255);
        atomicAdd(&hist[b0], 1u);
        atomicAdd(&hist[b1], 1u);
        atomicAdd(&hist[b2], 1u);
        atomicAdd(&hist[b3], 1u);
        if (write_v8) {
            uchar4 q;
            q.x = (unsigned char)min(max((int)floorf(v.x * 255.0f), 0), 255);
            q.y = (unsigned char)min(max((int)floorf(v.y * 255.0f), 0), 255);
            q.z = (unsigned char)min(max((int)floorf(v.z * 255.0f), 0), 255);
            q.w = (unsigned char)min(max((int)floorf(v.w * 255.0f), 0), 255);
            *reinterpret_cast<uchar4*>(v8base + (size_t)y * WW + x4 * 4) = q;
        }
    }
    __syncthreads();

    // Clip, then inclusive scan (Hillis-Steele over LDS, 8 steps).
    int ci = min((int)hist[t], CLIPV);
    scan[t] = ci;
    __syncthreads();
    for (int off = 1; off < 256; off <<= 1) {
        int add = (t >= off) ? scan[t - off] : 0;
        __syncthreads();
        scan[t] += add;
        __syncthreads();
    }
    int total    = scan[255];
    int excess   = PIXELS - total;           // >= 0
    int residual = excess & 255;
    int redist   = excess >> 8;
    // inclusive cumsum of (clipped + redist + (bin<residual ? 1 : 0))
    int cum = scan[t] + redist * (t + 1) + min(t + 1, residual);
    // (nb-1)/pixels = 255/4096 is exact in fp32; cum*scale <= 255 exactly.
    float lut = floorf(fminf((float)cum * (255.0f / 4096.0f), 255.0f));
    luts[(size_t)bid * NBINS + t] = lut;
}

// ---------------- Kernel 2: bilinear LUT application ---------------------------
__device__ __forceinline__ void axis_map(int pos, int& t0, int& t1, float& w) {
    // T=64, G=8: inside = [32, 480)
    if (pos < 32)        { t0 = 0; t1 = 0; w = 1.0f; }
    else if (pos >= 480) { t0 = 7; t1 = 7; w = 1.0f; }
    else {
        int k  = (pos - 32) >> 6;   // 0..6
        int rr = (pos - 32) & 63;
        t0 = k; t1 = k + 1;
        w  = (float)(63 - rr) / 63.0f;
    }
}

// One block = 4 consecutive rows of one (b,c) plane (2048 px), 8 px/thread.
// 4-aligned rows always share (ty0,ty1): tile-map breakpoints (32+64m, 480)
// are multiples of 4. Stage y-combined LUTs comb[r][tx][v] in LDS (32 KB).
template<bool USE_V8>
__global__ __launch_bounds__(256) void clahe_apply(const float* __restrict__ img,
                                                   const unsigned char* __restrict__ v8,
                                                   const float* __restrict__ luts,
                                                   float* __restrict__ out) {
    __shared__ float comb[4][8][NBINS];   // 32 KB -> 5 blocks/CU

    const int t     = threadIdx.x;
    const int bid   = blockIdx.x;
    const int rg    = bid & 127;          // row group 0..127
    const int plane = bid >> 7;           // b*3 + c, 0..95
    const int c     = plane % 3;
    const int bb    = plane / 3;
    const int y0    = rg * 4;

    int ty0, ty1; float wdum;
    axis_map(y0, ty0, ty1, wdum);
    float wy[4];
    #pragma unroll
    for (int r2 = 0; r2 < 4; ++r2) { int d0, d1; axis_map(y0 + r2, d0, d1, wy[r2]); }

    const int rowbase0 = (bb * 8 + ty0) * 8;
    const int rowbase1 = (bb * 8 + ty1) * 8;

    // ---- stage: 16 coalesced LUT loads per thread (v = t), 4 combined rows
    #pragma unroll
    for (int tx = 0; tx < 8; ++tx) {
        float L0 = luts[((size_t)((rowbase0 + tx) * 3 + c)) * NBINS + t];
        float L1 = luts[((size_t)((rowbase1 + tx) * 3 + c)) * NBINS + t];
        #pragma unroll
        for (int r2 = 0; r2 < 4; ++r2)
            comb[r2][tx][t] = wy[r2] * L0 + (1.0f - wy[r2]) * L1;
    }
    __syncthreads();

    // ---- apply: thread t -> row (t>>6) of group, pixels xb..xb+7
    const int row = t >> 6;
    const int xb  = (t & 63) * 8;
    const size_t p = ((size_t)plane << 18) + (size_t)(y0 + row) * WW + xb;

    // 8-aligned pixel group shares (tx0,tx1): x breakpoints are multiples of 8.
    int tx0, tx1; float wx0;
    axis_map(xb, tx0, tx1, wx0);
    const float* __restrict__ ptr0 = &comb[row][tx0][0];
    const float* __restrict__ ptr1 = &comb[row][tx1][0];

    int vv[8];
    if constexpr (USE_V8) {
        uint2 raw = *reinterpret_cast<const uint2*>(v8 + p);
        vv[0] =  raw.x        & 255;
        vv[1] = (raw.x >> 8)  & 255;
        vv[2] = (raw.x >> 16) & 255;
        vv[3] =  raw.x >> 24;
        vv[4] =  raw.y        & 255;
        vv[5] = (raw.y >> 8)  & 255;
        vv[6] = (raw.y >> 16) & 255;
        vv[7] =  raw.y >> 24;
    } else {
        float4 a = *reinterpret_cast<const float4*>(img + p);
        float4 b = *reinterpret_cast<const float4*>(img + p + 4);
        float pix[8] = {a.x, a.y, a.z, a.w, b.x, b.y, b.z, b.w};
        #pragma unroll
        for (int i = 0; i < 8; ++i)
            vv[i] = min(max((int)floorf(pix[i] * 255.0f), 0), 255);
    }

    float res[8];
    #pragma unroll
    for (int i = 0; i < 8; ++i) {
        int xx = xb + i;
        float wx;
        if (xx < 32 || xx >= 480) wx = 1.0f;
        else                      wx = (float)(63 - ((xx - 32) & 63)) / 63.0f;
        float Lr0 = ptr0[vv[i]];
        float Lr1 = ptr1[vv[i]];
        res[i] = (wx * Lr0 + (1.0f - wx) * Lr1) * (1.0f / 255.0f);
    }
    *reinterpret_cast<float4*>(out + p)     = make_float4(res[0], res[1], res[2], res[3]);
    *reinterpret_cast<float4*>(out + p + 4) = make_float4(res[4], res[5], res[6], res[7]);
}

extern "C" void kernel_launch(void* const* d_in, const int* in_sizes, int n_in,
                              void* d_out, int out_size, void* d_ws, size_t ws_size,
                              hipStream_t stream) {
    const float* img  = (const float*)d_in[0];
    float*       out  = (float*)d_out;
    float*       luts = (float*)d_ws;
    unsigned char* v8 = (unsigned char*)d_ws + (size_t)LUTS_FLOATS * 4;

    const bool use_v8 = ws_size >= (size_t)LUTS_FLOATS * 4 + V8_BYTES;

    // Kernel 1: one block per (b,ty,tx,c)
    clahe_hist_lut<<<32 * 8 * 8 * 3, 256, 0, stream>>>(img, luts, v8, use_v8 ? 1 : 0);
    // Kernel 2: one block per (plane, 4-row group): 96 * 128 = 12288 blocks
    if (use_v8)
        clahe_apply<true><<<12288, 256, 0, stream>>>(img, v8, luts, out);
    else
        clahe_apply<false><<<12288, 256, 0, stream>>>(img, v8, luts, out);
}